// Round 1
// 1091.496 us; speedup vs baseline: 1.3536x; 1.3536x over previous
//
#include <hip/hip_runtime.h>
#include <hip/hip_bf16.h>
#include <stdint.h>

#define N_NODES 100000
#define N_EDGES 3200000
#define ALPHA   0.1f

typedef __attribute__((ext_vector_type(8))) short v8s;   // 8 x bf16
typedef __attribute__((ext_vector_type(4))) float f32x4; // MFMA acc

__device__ __forceinline__ uint32_t bf16_rne(float f) {
    uint32_t u = __float_as_uint(f);
    return (u + 0x7FFFu + ((u >> 16) & 1u)) >> 16;
}
__device__ __forceinline__ float bf16_f32(uint32_t b) { return __uint_as_float(b << 16); }

// ---------------------------------------------------------------------------
// W1 [256][512] fp32 -> A-fragment-ordered hi/lo bf16 chunks in global.
// ---------------------------------------------------------------------------
__global__ __launch_bounds__(256) void w1_frag_kernel(
    const float* __restrict__ W1, uint4* __restrict__ W1f)
{
    int tid = blockIdx.x * 256 + threadIdx.x;   // 16384
    int ks = tid >> 10, T = (tid >> 6) & 15, l = tid & 63;
    int row = T * 16 + (l & 15);
    int kb  = ks * 32 + (l >> 4) * 8;
    const float* src = W1 + (size_t)row * 512 + kb;
    float4 f0 = *(const float4*)(src);
    float4 f1 = *(const float4*)(src + 4);
    float f[8] = {f0.x, f0.y, f0.z, f0.w, f1.x, f1.y, f1.z, f1.w};
    uint32_t hi[8], lo[8];
#pragma unroll
    for (int j = 0; j < 8; ++j) {
        hi[j] = bf16_rne(f[j]);
        lo[j] = bf16_rne(f[j] - bf16_f32(hi[j]));
    }
    uint4 H = make_uint4(hi[0] | (hi[1] << 16), hi[2] | (hi[3] << 16),
                         hi[4] | (hi[5] << 16), hi[6] | (hi[7] << 16));
    uint4 L = make_uint4(lo[0] | (lo[1] << 16), lo[2] | (lo[3] << 16),
                         lo[4] | (lo[5] << 16), lo[6] | (lo[7] << 16));
    size_t base = ((size_t)(ks * 2) * 16 + T) * 64 + l;
    W1f[base]        = H;
    W1f[base + 1024] = L;   // p=1 plane
}

// ---------------------------------------------------------------------------
// MLP: h = relu(x@W1^T+b1)@W2^T+b2 via MFMA 16x16x32 bf16 hi/lo split.
// GEMM2 epilogue in 4-class chunks (16 live floats).
// ---------------------------------------------------------------------------
__global__ __launch_bounds__(256, 2) void mlp_kernel(
    const float* __restrict__ x, const uint4* __restrict__ W1f,
    const float* __restrict__ b1, const float* __restrict__ W2,
    const float* __restrict__ b2, const float* __restrict__ dinv,
    float* __restrict__ h, float* __restrict__ hs, int n)
{
    __shared__ __align__(16) char smem[33280];
    char*  xs   = smem;                    // K-loop: hi plane 4096 + lo plane 4096
    float* W2s  = (float*)smem;            // epilogue: [16][260] = 16640 B
    float* part = (float*)(smem + 16640);  // epilogue: [4][64][16] = 16384 B

    const int tid = threadIdx.x;
    const int w = tid >> 6, l = tid & 63;
    const int l15 = l & 15, q = l >> 4;
    const int row0 = blockIdx.x * 64;

    const int s_l15 = tid & 15;
    const int s_seg = (tid >> 4) & 3;
    const int s_u   = tid >> 6;
    const int s_grow = row0 + s_u * 16 + s_l15;

    f32x4 acc[4][4];
#pragma unroll
    for (int mt = 0; mt < 4; ++mt)
#pragma unroll
        for (int nt = 0; nt < 4; ++nt) acc[mt][nt] = (f32x4){0.f, 0.f, 0.f, 0.f};

    for (int ks = 0; ks < 16; ++ks) {
        uint4 aHu[4], aLu[4];
#pragma unroll
        for (int mt = 0; mt < 4; ++mt) {
            size_t cidx = ((size_t)(ks * 2) * 16 + (w * 4 + mt)) * 64 + l;
            aHu[mt] = W1f[cidx];
            aLu[mt] = W1f[cidx + 1024];
        }
        float4 f0 = make_float4(0.f, 0.f, 0.f, 0.f), f1 = f0;
        if (s_grow < n) {
            const float* xp = x + (size_t)s_grow * 512 + ks * 32 + s_seg * 8;
            f0 = *(const float4*)(xp);
            f1 = *(const float4*)(xp + 4);
        }
        float f[8] = {f0.x, f0.y, f0.z, f0.w, f1.x, f1.y, f1.z, f1.w};
        uint32_t hi[8], lo[8];
#pragma unroll
        for (int j = 0; j < 8; ++j) {
            hi[j] = bf16_rne(f[j]);
            lo[j] = bf16_rne(f[j] - bf16_f32(hi[j]));
        }
        uint4 H = make_uint4(hi[0] | (hi[1] << 16), hi[2] | (hi[3] << 16),
                             hi[4] | (hi[5] << 16), hi[6] | (hi[7] << 16));
        uint4 L = make_uint4(lo[0] | (lo[1] << 16), lo[2] | (lo[3] << 16),
                             lo[4] | (lo[5] << 16), lo[6] | (lo[7] << 16));
        __syncthreads();
        *(uint4*)(xs +        s_u * 1024 + (s_seg * 16 + s_l15) * 16) = H;
        *(uint4*)(xs + 4096 + s_u * 1024 + (s_seg * 16 + s_l15) * 16) = L;
        __syncthreads();

        v8s bH[4], bL[4];
#pragma unroll
        for (int nt = 0; nt < 4; ++nt) {
            bH[nt] = *(v8s*)(xs +        nt * 1024 + l * 16);
            bL[nt] = *(v8s*)(xs + 4096 + nt * 1024 + l * 16);
        }
#pragma unroll
        for (int mt = 0; mt < 4; ++mt) {
            v8s aH = *(v8s*)&aHu[mt];
            v8s aL = *(v8s*)&aLu[mt];
#pragma unroll
            for (int nt = 0; nt < 4; ++nt) {
                f32x4 c = acc[mt][nt];
                c = __builtin_amdgcn_mfma_f32_16x16x32_bf16(aH, bH[nt], c, 0, 0, 0);
                c = __builtin_amdgcn_mfma_f32_16x16x32_bf16(aH, bL[nt], c, 0, 0, 0);
                c = __builtin_amdgcn_mfma_f32_16x16x32_bf16(aL, bH[nt], c, 0, 0, 0);
                acc[mt][nt] = c;
            }
        }
    }

#pragma unroll
    for (int mt = 0; mt < 4; ++mt) {
        float4 bv = *(const float4*)(b1 + w * 64 + mt * 16 + q * 4);
#pragma unroll
        for (int nt = 0; nt < 4; ++nt) {
            acc[mt][nt][0] = fmaxf(acc[mt][nt][0] + bv.x, 0.f);
            acc[mt][nt][1] = fmaxf(acc[mt][nt][1] + bv.y, 0.f);
            acc[mt][nt][2] = fmaxf(acc[mt][nt][2] + bv.z, 0.f);
            acc[mt][nt][3] = fmaxf(acc[mt][nt][3] + bv.w, 0.f);
        }
    }

    __syncthreads();
    {
        int c = tid >> 4, k16 = (tid & 15) * 16;
#pragma unroll
        for (int i = 0; i < 4; ++i)
            *(float4*)(W2s + c * 260 + k16 + i * 4) =
                *(const float4*)(W2 + c * 256 + k16 + i * 4);
    }
    __syncthreads();

#pragma unroll
    for (int c4 = 0; c4 < 4; ++c4) {
        float p2[4][4];
#pragma unroll
        for (int nt = 0; nt < 4; ++nt)
#pragma unroll
            for (int cc = 0; cc < 4; ++cc) p2[nt][cc] = 0.f;
#pragma unroll
        for (int mt = 0; mt < 4; ++mt)
#pragma unroll
            for (int cc = 0; cc < 4; ++cc) {
                float4 wv = *(float4*)(W2s + (c4 * 4 + cc) * 260 + w * 64 + mt * 16 + q * 4);
#pragma unroll
                for (int nt = 0; nt < 4; ++nt)
                    p2[nt][cc] += acc[mt][nt][0] * wv.x + acc[mt][nt][1] * wv.y +
                                  acc[mt][nt][2] * wv.z + acc[mt][nt][3] * wv.w;
            }
#pragma unroll
        for (int nt = 0; nt < 4; ++nt)
#pragma unroll
            for (int cc = 0; cc < 4; ++cc) {
                p2[nt][cc] += __shfl_xor(p2[nt][cc], 16);
                p2[nt][cc] += __shfl_xor(p2[nt][cc], 32);
            }
        if (q == c4) {
#pragma unroll
            for (int nt = 0; nt < 4; ++nt)
                *(float4*)(part + ((w * 64 + nt * 16 + l15) << 4) + c4 * 4) =
                    make_float4(p2[nt][0], p2[nt][1], p2[nt][2], p2[nt][3]);
        }
    }
    __syncthreads();
    {
        int node = tid >> 2, c4 = (tid & 3) * 4;
        float4 s = make_float4(0.f, 0.f, 0.f, 0.f);
#pragma unroll
        for (int ww = 0; ww < 4; ++ww) {
            float4 v = *(float4*)(part + ((ww * 64 + node) << 4) + c4);
            s.x += v.x; s.y += v.y; s.z += v.z; s.w += v.w;
        }
        float4 bv = *(const float4*)(b2 + c4);
        int grow = row0 + node;
        if (grow < n) {
            float4 hv = make_float4(s.x + bv.x, s.y + bv.y, s.z + bv.z, s.w + bv.w);
            *(float4*)(h + (size_t)grow * 16 + c4) = hv;
            float di = dinv[grow];
            *(float4*)(hs + (size_t)grow * 16 + c4) =
                make_float4(di * hv.x, di * hv.y, di * hv.z, di * hv.w);
        }
    }
}

// ---------------------------------------------------------------------------
// CSR build
// ---------------------------------------------------------------------------
__global__ void hist_kernel(const int* __restrict__ dst, int* __restrict__ cnt, int e)
{
    int i = blockIdx.x * blockDim.x + threadIdx.x;
    if (i < e) atomicAdd(&cnt[dst[i]], 1);
}

__global__ void dinv_kernel(const int* __restrict__ cnt, float* __restrict__ dinv, int n)
{
    int i = blockIdx.x * blockDim.x + threadIdx.x;
    if (i < n) dinv[i] = rsqrtf((float)cnt[i] + 1.0f);  // +1 self-loop
}

// multi-block exclusive scan (3 phases)
__global__ __launch_bounds__(256) void scan1_kernel(
    const int* __restrict__ cnt, int* __restrict__ row_loc,
    int* __restrict__ bsum, int n)
{
    __shared__ int sm[256];
    int i = blockIdx.x * 256 + threadIdx.x;
    int v = (i < n) ? cnt[i] : 0;
    sm[threadIdx.x] = v;
    __syncthreads();
#pragma unroll
    for (int off = 1; off < 256; off <<= 1) {
        int t = (threadIdx.x >= off) ? sm[threadIdx.x - off] : 0;
        __syncthreads();
        sm[threadIdx.x] += t;
        __syncthreads();
    }
    if (i < n) row_loc[i] = sm[threadIdx.x] - v;
    if (threadIdx.x == 255) bsum[blockIdx.x] = sm[255];
}

__global__ __launch_bounds__(512) void scan2_kernel(
    const int* __restrict__ bsum, int* __restrict__ boff, int nb)
{
    __shared__ int sm[512];
    int i = threadIdx.x;
    int v = (i < nb) ? bsum[i] : 0;
    sm[i] = v;
    __syncthreads();
#pragma unroll
    for (int off = 1; off < 512; off <<= 1) {
        int t = (i >= off) ? sm[i - off] : 0;
        __syncthreads();
        sm[i] += t;
        __syncthreads();
    }
    if (i < nb) boff[i] = sm[i] - v;
}

__global__ void scan3_kernel(int* __restrict__ row_st, const int* __restrict__ boff,
                             int* __restrict__ cursor, int n, int e)
{
    int i = blockIdx.x * blockDim.x + threadIdx.x;
    if (i < n) {
        int r = row_st[i] + boff[i >> 8];
        row_st[i] = r;
        cursor[i] = r;
    }
    if (i == 0) row_st[n] = e;
}

// ---------------------------------------------------------------------------
// XCD-windowed scatter: block b = chunk (b>>3) x dst-window (b&7).
// Now writes only the 4B src index (dst is implied by CSR row).
// ---------------------------------------------------------------------------
#define SC_CHUNK 2048
__global__ __launch_bounds__(256) void scatter8_kernel(
    const int* __restrict__ src, const int* __restrict__ dst,
    int* __restrict__ cursor, int* __restrict__ csr_s, int e)
{
    const int w    = blockIdx.x & 7;
    const int base = (blockIdx.x >> 3) * SC_CHUNK;
    const int wlo  = w * (N_NODES / 8);
    const int whi  = wlo + (N_NODES / 8);
#pragma unroll
    for (int t = 0; t < SC_CHUNK / 256; ++t) {
        int i = base + t * 256 + threadIdx.x;
        if (i < e) {
            int d = dst[i];
            if (d >= wlo && d < whi) {
                int s = src[i];
                int pos = atomicAdd(&cursor[d], 1);
                csr_s[pos] = s;
            }
        }
    }
}

// ---------------------------------------------------------------------------
// Node-parallel pull propagation. One 4-lane quad per node; each lane owns 4
// of the 16 classes. Serial loop over the node's CSR edges: int4 index loads
// (4 edges per load after head alignment) + 4 independent float4 gathers in
// flight per group. No LDS, no barriers, no spill fixup kernel.
// zs_in = dinv*z; out = dinv*z_next (or log_softmax on the last step).
// ---------------------------------------------------------------------------
__global__ __launch_bounds__(256) void prop_kernel(
    const int* __restrict__ csr_s, const int* __restrict__ row_st,
    const float* __restrict__ dinv, const float* __restrict__ zs_in,
    const float* __restrict__ hmat, float* __restrict__ out,
    int n, int is_last)
{
    const int d = blockIdx.x * 64 + (threadIdx.x >> 2);
    if (d >= n) return;
    const int f4 = (threadIdx.x & 3) * 4;
    const int rs = row_st[d], re = row_st[d + 1];

    // self-loop contribution
    float4 S = *(const float4*)(zs_in + (size_t)d * 16 + f4);

    int j = rs;
    // align j to 4 for int4 index loads
    int head = (rs + 3) & ~3;
    if (head > re) head = re;
    for (; j < head; ++j) {
        int s0 = csr_s[j];
        const float4 a = *(const float4*)(zs_in + (size_t)s0 * 16 + f4);
        S.x += a.x; S.y += a.y; S.z += a.z; S.w += a.w;
    }
    for (; j + 4 <= re; j += 4) {
        int4 sv = *(const int4*)(csr_s + j);
        const float4 a = *(const float4*)(zs_in + (size_t)sv.x * 16 + f4);
        const float4 b = *(const float4*)(zs_in + (size_t)sv.y * 16 + f4);
        const float4 c = *(const float4*)(zs_in + (size_t)sv.z * 16 + f4);
        const float4 e = *(const float4*)(zs_in + (size_t)sv.w * 16 + f4);
        S.x += (a.x + b.x) + (c.x + e.x);
        S.y += (a.y + b.y) + (c.y + e.y);
        S.z += (a.z + b.z) + (c.z + e.z);
        S.w += (a.w + b.w) + (c.w + e.w);
    }
    for (; j < re; ++j) {
        int s0 = csr_s[j];
        const float4 a = *(const float4*)(zs_in + (size_t)s0 * 16 + f4);
        S.x += a.x; S.y += a.y; S.z += a.z; S.w += a.w;
    }

    const float di = dinv[d];
    const float4 hv = *(const float4*)(hmat + (size_t)d * 16 + f4);
    float4 zn;
    zn.x = fmaf(1.0f - ALPHA, di * S.x, ALPHA * hv.x);
    zn.y = fmaf(1.0f - ALPHA, di * S.y, ALPHA * hv.y);
    zn.z = fmaf(1.0f - ALPHA, di * S.z, ALPHA * hv.z);
    zn.w = fmaf(1.0f - ALPHA, di * S.w, ALPHA * hv.w);
    if (!is_last) {
        *(float4*)(out + (size_t)d * 16 + f4) =
            make_float4(di * zn.x, di * zn.y, di * zn.z, di * zn.w);
    } else {
        float m = fmaxf(fmaxf(zn.x, zn.y), fmaxf(zn.z, zn.w));
        m = fmaxf(m, __shfl_xor(m, 1));
        m = fmaxf(m, __shfl_xor(m, 2));
        float ss = expf(zn.x - m) + expf(zn.y - m) + expf(zn.z - m) + expf(zn.w - m);
        ss += __shfl_xor(ss, 1);
        ss += __shfl_xor(ss, 2);
        float ls = logf(ss);
        *(float4*)(out + (size_t)d * 16 + f4) =
            make_float4(zn.x - m - ls, zn.y - m - ls, zn.z - m - ls, zn.w - m - ls);
    }
}

// ---------------------------------------------------------------------------
extern "C" void kernel_launch(void* const* d_in, const int* in_sizes, int n_in,
                              void* d_out, int out_size, void* d_ws, size_t ws_size,
                              hipStream_t stream)
{
    const float* x  = (const float*)d_in[0];
    const float* W1 = (const float*)d_in[1];
    const float* b1 = (const float*)d_in[2];
    const float* W2 = (const float*)d_in[3];
    const float* b2 = (const float*)d_in[4];
    const int*   ei = (const int*)d_in[5];

    const int N = N_NODES;
    const int E = N_EDGES;
    const int* srcp = ei;
    const int* dstp = ei + E;

    float* ws = (float*)d_ws;
    float* h       = ws;                        // 1,600,000 f
    float* ZSA     = ws + 1600000;              // 1,600,000 f
    float* ZSB     = ws + 3200000;              // 1,600,000 f  (starts as hs)
    float* dinv    = ws + 4800000;              // 100,000 f
    int*   row_st  = (int*)(ws + 4900000);      // 100,001 i (pad 100004)
    int*   csr_s   = (int*)(ws + 5000004);      // 3,200,000 x 4B
    // transient overlays:
    int*   cnt     = (int*)(ws);                // in h region
    int*   cursor  = (int*)(ws + 100000);       // in h region
    int*   bsum    = (int*)(ws + 200000);       // in h region (512)
    int*   boff    = (int*)(ws + 200512);       // in h region (512)
    uint4* W1f     = (uint4*)(ws + 1600000);    // in ZSA region (dead before step 0)

    const int NB_SCAN = (N + 255) / 256;        // 391

    hipMemsetAsync(cnt, 0, (size_t)N * sizeof(int), stream);
    hist_kernel<<<(E + 255) / 256, 256, 0, stream>>>(dstp, cnt, E);
    dinv_kernel<<<(N + 255) / 256, 256, 0, stream>>>(cnt, dinv, N);
    scan1_kernel<<<NB_SCAN, 256, 0, stream>>>(cnt, row_st, bsum, N);
    scan2_kernel<<<1, 512, 0, stream>>>(bsum, boff, NB_SCAN);
    scan3_kernel<<<(N + 255) / 256, 256, 0, stream>>>(row_st, boff, cursor, N, E);
    {
        const int nchunks = (E + SC_CHUNK - 1) / SC_CHUNK;   // 1563
        scatter8_kernel<<<nchunks * 8, 256, 0, stream>>>(srcp, dstp, cursor, csr_s, E);
    }
    w1_frag_kernel<<<64, 256, 0, stream>>>(W1, W1f);
    mlp_kernel<<<(N + 63) / 64, 256, 0, stream>>>(x, W1f, b1, W2, b2, dinv, h, ZSB, N);

    const int NB_PROP = (N + 63) / 64;   // 1563
    for (int k = 0; k < 10; ++k) {
        const int last = (k == 9) ? 1 : 0;
        const float* zin = (k == 0) ? ZSB : ((k & 1) ? ZSA : ZSB);
        float* zo = last ? (float*)d_out : ((k & 1) ? ZSB : ZSA);
        prop_kernel<<<NB_PROP, 256, 0, stream>>>(csr_s, row_st, dinv, zin, h, zo,
                                                 N, last);
    }
}

// Round 3
// 977.164 us; speedup vs baseline: 1.5120x; 1.1170x over previous
//
#include <hip/hip_runtime.h>
#include <hip/hip_bf16.h>
#include <stdint.h>

#define N_NODES 100000
#define N_EDGES 3200000
#define ALPHA   0.1f

typedef __attribute__((ext_vector_type(8))) short v8s;   // 8 x bf16
typedef __attribute__((ext_vector_type(4))) float f32x4; // MFMA acc

__device__ __forceinline__ uint32_t bf16_rne(float f) {
    uint32_t u = __float_as_uint(f);
    return (u + 0x7FFFu + ((u >> 16) & 1u)) >> 16;
}
__device__ __forceinline__ float bf16_f32(uint32_t b) { return __uint_as_float(b << 16); }

// ---------------------------------------------------------------------------
// W1 [256][512] fp32 -> A-fragment-ordered hi/lo bf16 chunks in global.
// ---------------------------------------------------------------------------
__global__ __launch_bounds__(256) void w1_frag_kernel(
    const float* __restrict__ W1, uint4* __restrict__ W1f)
{
    int tid = blockIdx.x * 256 + threadIdx.x;   // 16384
    int ks = tid >> 10, T = (tid >> 6) & 15, l = tid & 63;
    int row = T * 16 + (l & 15);
    int kb  = ks * 32 + (l >> 4) * 8;
    const float* src = W1 + (size_t)row * 512 + kb;
    float4 f0 = *(const float4*)(src);
    float4 f1 = *(const float4*)(src + 4);
    float f[8] = {f0.x, f0.y, f0.z, f0.w, f1.x, f1.y, f1.z, f1.w};
    uint32_t hi[8], lo[8];
#pragma unroll
    for (int j = 0; j < 8; ++j) {
        hi[j] = bf16_rne(f[j]);
        lo[j] = bf16_rne(f[j] - bf16_f32(hi[j]));
    }
    uint4 H = make_uint4(hi[0] | (hi[1] << 16), hi[2] | (hi[3] << 16),
                         hi[4] | (hi[5] << 16), hi[6] | (hi[7] << 16));
    uint4 L = make_uint4(lo[0] | (lo[1] << 16), lo[2] | (lo[3] << 16),
                         lo[4] | (lo[5] << 16), lo[6] | (lo[7] << 16));
    size_t base = ((size_t)(ks * 2) * 16 + T) * 64 + l;
    W1f[base]        = H;
    W1f[base + 1024] = L;   // p=1 plane
}

// ---------------------------------------------------------------------------
// MLP: h = relu(x@W1^T+b1)@W2^T+b2 via MFMA 16x16x32 bf16 hi/lo split.
// ---------------------------------------------------------------------------
__global__ __launch_bounds__(256, 2) void mlp_kernel(
    const float* __restrict__ x, const uint4* __restrict__ W1f,
    const float* __restrict__ b1, const float* __restrict__ W2,
    const float* __restrict__ b2, const float* __restrict__ dinv,
    float* __restrict__ h, float* __restrict__ hs, int n)
{
    __shared__ __align__(16) char smem[33280];
    char*  xs   = smem;                    // K-loop: hi plane 4096 + lo plane 4096
    float* W2s  = (float*)smem;            // epilogue: [16][260] = 16640 B
    float* part = (float*)(smem + 16640);  // epilogue: [4][64][16] = 16384 B

    const int tid = threadIdx.x;
    const int w = tid >> 6, l = tid & 63;
    const int l15 = l & 15, q = l >> 4;
    const int row0 = blockIdx.x * 64;

    const int s_l15 = tid & 15;
    const int s_seg = (tid >> 4) & 3;
    const int s_u   = tid >> 6;
    const int s_grow = row0 + s_u * 16 + s_l15;

    f32x4 acc[4][4];
#pragma unroll
    for (int mt = 0; mt < 4; ++mt)
#pragma unroll
        for (int nt = 0; nt < 4; ++nt) acc[mt][nt] = (f32x4){0.f, 0.f, 0.f, 0.f};

    for (int ks = 0; ks < 16; ++ks) {
        uint4 aHu[4], aLu[4];
#pragma unroll
        for (int mt = 0; mt < 4; ++mt) {
            size_t cidx = ((size_t)(ks * 2) * 16 + (w * 4 + mt)) * 64 + l;
            aHu[mt] = W1f[cidx];
            aLu[mt] = W1f[cidx + 1024];
        }
        float4 f0 = make_float4(0.f, 0.f, 0.f, 0.f), f1 = f0;
        if (s_grow < n) {
            const float* xp = x + (size_t)s_grow * 512 + ks * 32 + s_seg * 8;
            f0 = *(const float4*)(xp);
            f1 = *(const float4*)(xp + 4);
        }
        float f[8] = {f0.x, f0.y, f0.z, f0.w, f1.x, f1.y, f1.z, f1.w};
        uint32_t hi[8], lo[8];
#pragma unroll
        for (int j = 0; j < 8; ++j) {
            hi[j] = bf16_rne(f[j]);
            lo[j] = bf16_rne(f[j] - bf16_f32(hi[j]));
        }
        uint4 H = make_uint4(hi[0] | (hi[1] << 16), hi[2] | (hi[3] << 16),
                             hi[4] | (hi[5] << 16), hi[6] | (hi[7] << 16));
        uint4 L = make_uint4(lo[0] | (lo[1] << 16), lo[2] | (lo[3] << 16),
                             lo[4] | (lo[5] << 16), lo[6] | (lo[7] << 16));
        __syncthreads();
        *(uint4*)(xs +        s_u * 1024 + (s_seg * 16 + s_l15) * 16) = H;
        *(uint4*)(xs + 4096 + s_u * 1024 + (s_seg * 16 + s_l15) * 16) = L;
        __syncthreads();

        v8s bH[4], bL[4];
#pragma unroll
        for (int nt = 0; nt < 4; ++nt) {
            bH[nt] = *(v8s*)(xs +        nt * 1024 + l * 16);
            bL[nt] = *(v8s*)(xs + 4096 + nt * 1024 + l * 16);
        }
#pragma unroll
        for (int mt = 0; mt < 4; ++mt) {
            v8s aH = *(v8s*)&aHu[mt];
            v8s aL = *(v8s*)&aLu[mt];
#pragma unroll
            for (int nt = 0; nt < 4; ++nt) {
                f32x4 c = acc[mt][nt];
                c = __builtin_amdgcn_mfma_f32_16x16x32_bf16(aH, bH[nt], c, 0, 0, 0);
                c = __builtin_amdgcn_mfma_f32_16x16x32_bf16(aH, bL[nt], c, 0, 0, 0);
                c = __builtin_amdgcn_mfma_f32_16x16x32_bf16(aL, bH[nt], c, 0, 0, 0);
                acc[mt][nt] = c;
            }
        }
    }

#pragma unroll
    for (int mt = 0; mt < 4; ++mt) {
        float4 bv = *(const float4*)(b1 + w * 64 + mt * 16 + q * 4);
#pragma unroll
        for (int nt = 0; nt < 4; ++nt) {
            acc[mt][nt][0] = fmaxf(acc[mt][nt][0] + bv.x, 0.f);
            acc[mt][nt][1] = fmaxf(acc[mt][nt][1] + bv.y, 0.f);
            acc[mt][nt][2] = fmaxf(acc[mt][nt][2] + bv.z, 0.f);
            acc[mt][nt][3] = fmaxf(acc[mt][nt][3] + bv.w, 0.f);
        }
    }

    __syncthreads();
    {
        int c = tid >> 4, k16 = (tid & 15) * 16;
#pragma unroll
        for (int i = 0; i < 4; ++i)
            *(float4*)(W2s + c * 260 + k16 + i * 4) =
                *(const float4*)(W2 + c * 256 + k16 + i * 4);
    }
    __syncthreads();

#pragma unroll
    for (int c4 = 0; c4 < 4; ++c4) {
        float p2[4][4];
#pragma unroll
        for (int nt = 0; nt < 4; ++nt)
#pragma unroll
            for (int cc = 0; cc < 4; ++cc) p2[nt][cc] = 0.f;
#pragma unroll
        for (int mt = 0; mt < 4; ++mt)
#pragma unroll
            for (int cc = 0; cc < 4; ++cc) {
                float4 wv = *(float4*)(W2s + (c4 * 4 + cc) * 260 + w * 64 + mt * 16 + q * 4);
#pragma unroll
                for (int nt = 0; nt < 4; ++nt)
                    p2[nt][cc] += acc[mt][nt][0] * wv.x + acc[mt][nt][1] * wv.y +
                                  acc[mt][nt][2] * wv.z + acc[mt][nt][3] * wv.w;
            }
#pragma unroll
        for (int nt = 0; nt < 4; ++nt)
#pragma unroll
            for (int cc = 0; cc < 4; ++cc) {
                p2[nt][cc] += __shfl_xor(p2[nt][cc], 16);
                p2[nt][cc] += __shfl_xor(p2[nt][cc], 32);
            }
        if (q == c4) {
#pragma unroll
            for (int nt = 0; nt < 4; ++nt)
                *(float4*)(part + ((w * 64 + nt * 16 + l15) << 4) + c4 * 4) =
                    make_float4(p2[nt][0], p2[nt][1], p2[nt][2], p2[nt][3]);
        }
    }
    __syncthreads();
    {
        int node = tid >> 2, c4 = (tid & 3) * 4;
        float4 s = make_float4(0.f, 0.f, 0.f, 0.f);
#pragma unroll
        for (int ww = 0; ww < 4; ++ww) {
            float4 v = *(float4*)(part + ((ww * 64 + node) << 4) + c4);
            s.x += v.x; s.y += v.y; s.z += v.z; s.w += v.w;
        }
        float4 bv = *(const float4*)(b2 + c4);
        int grow = row0 + node;
        if (grow < n) {
            float4 hv = make_float4(s.x + bv.x, s.y + bv.y, s.z + bv.z, s.w + bv.w);
            *(float4*)(h + (size_t)grow * 16 + c4) = hv;
            float di = dinv[grow];
            *(float4*)(hs + (size_t)grow * 16 + c4) =
                make_float4(di * hv.x, di * hv.y, di * hv.z, di * hv.w);
        }
    }
}

// ---------------------------------------------------------------------------
// CSR build
// ---------------------------------------------------------------------------
__global__ void hist_kernel(const int* __restrict__ dst, int* __restrict__ cnt, int e)
{
    int i = blockIdx.x * blockDim.x + threadIdx.x;
    if (i < e) atomicAdd(&cnt[dst[i]], 1);
}

// dinv from REAL degree; padded (mult-of-16) counts for CSR; zero dummy zs rows.
__global__ void dinv_kernel(const int* __restrict__ cnt, float* __restrict__ dinv,
                            int* __restrict__ pcnt,
                            float* __restrict__ zsA_dummy, float* __restrict__ zsB_dummy,
                            int n)
{
    int i = blockIdx.x * blockDim.x + threadIdx.x;
    if (i < n) {
        int c = cnt[i];
        dinv[i] = rsqrtf((float)c + 1.0f);  // +1 self-loop
        pcnt[i] = (c + 15) & ~15;
    }
    if (i < 16) { zsA_dummy[i] = 0.0f; zsB_dummy[i] = 0.0f; }
}

// fill csr pad region with the dummy node index
__global__ void fill_kernel(int4* __restrict__ p, int v, int cnt4)
{
    int i = blockIdx.x * blockDim.x + threadIdx.x;
    if (i < cnt4) p[i] = make_int4(v, v, v, v);
}

// multi-block exclusive scan over pcnt (3 phases), covers i <= n
__global__ __launch_bounds__(256) void scan1_kernel(
    const int* __restrict__ pcnt, int* __restrict__ row_loc,
    int* __restrict__ bsum, int n)
{
    __shared__ int sm[256];
    int i = blockIdx.x * 256 + threadIdx.x;
    int v = (i < n) ? pcnt[i] : 0;
    sm[threadIdx.x] = v;
    __syncthreads();
#pragma unroll
    for (int off = 1; off < 256; off <<= 1) {
        int t = (threadIdx.x >= off) ? sm[threadIdx.x - off] : 0;
        __syncthreads();
        sm[threadIdx.x] += t;
        __syncthreads();
    }
    if (i <= n) row_loc[i] = sm[threadIdx.x] - v;
    if (threadIdx.x == 255) bsum[blockIdx.x] = sm[255];
}

__global__ __launch_bounds__(512) void scan2_kernel(
    const int* __restrict__ bsum, int* __restrict__ boff, int nb)
{
    __shared__ int sm[512];
    int i = threadIdx.x;
    int v = (i < nb) ? bsum[i] : 0;
    sm[i] = v;
    __syncthreads();
#pragma unroll
    for (int off = 1; off < 512; off <<= 1) {
        int t = (i >= off) ? sm[i - off] : 0;
        __syncthreads();
        sm[i] += t;
        __syncthreads();
    }
    if (i < nb) boff[i] = sm[i] - v;
}

__global__ void scan3_kernel(int* __restrict__ row_st, const int* __restrict__ boff,
                             int* __restrict__ cursor, int n)
{
    int i = blockIdx.x * blockDim.x + threadIdx.x;
    if (i <= n) {
        int r = row_st[i] + boff[i >> 8];
        row_st[i] = r;
        if (i < n) cursor[i] = r;
    }
}

// ---------------------------------------------------------------------------
// XCD-windowed scatter: block b = chunk (b>>3) x dst-window (b&7).
// Writes only the 4B src index (dst implied by CSR row).
// ---------------------------------------------------------------------------
#define SC_CHUNK 2048
__global__ __launch_bounds__(256) void scatter8_kernel(
    const int* __restrict__ src, const int* __restrict__ dst,
    int* __restrict__ cursor, int* __restrict__ csr_s, int e)
{
    const int w    = blockIdx.x & 7;
    const int base = (blockIdx.x >> 3) * SC_CHUNK;
    const int wlo  = w * (N_NODES / 8);
    const int whi  = wlo + (N_NODES / 8);
#pragma unroll
    for (int t = 0; t < SC_CHUNK / 256; ++t) {
        int i = base + t * 256 + threadIdx.x;
        if (i < e) {
            int d = dst[i];
            if (d >= wlo && d < whi) {
                int s = src[i];
                int pos = atomicAdd(&cursor[d], 1);
                csr_s[pos] = s;
            }
        }
    }
}

// ---------------------------------------------------------------------------
// Node-parallel pull, 16 lanes/node (4 subs x 4 class-lanes). CSR rows are
// padded to a multiple of 16 with dummy edges -> uniform loop, int4-aligned,
// zero divergence. Unroll-2 keeps 8 gathers in flight per lane. Partial sums
// combined with shfl_xor(4,8).
// ---------------------------------------------------------------------------
__global__ __launch_bounds__(256) void prop_kernel(
    const int* __restrict__ csr_s, const int* __restrict__ row_st,
    const float* __restrict__ dinv, const float* __restrict__ zs_in,
    const float* __restrict__ hmat, float* __restrict__ out,
    int n, int is_last)
{
    const int t = threadIdx.x;
    const int d = blockIdx.x * 16 + (t >> 4);
    if (d >= n) return;
    const int lane16 = t & 15;
    const int sub = lane16 >> 2;
    const int f4 = (lane16 & 3) * 4;
    const int rs = row_st[d], re = row_st[d + 1];

    float4 S = make_float4(0.f, 0.f, 0.f, 0.f);
    int j = rs + sub * 4;
    for (; j + 16 < re; j += 32) {
        int4 s0 = *(const int4*)(csr_s + j);
        int4 s1 = *(const int4*)(csr_s + j + 16);
        const float4 a0 = *(const float4*)(zs_in + (size_t)s0.x * 16 + f4);
        const float4 b0 = *(const float4*)(zs_in + (size_t)s0.y * 16 + f4);
        const float4 c0 = *(const float4*)(zs_in + (size_t)s0.z * 16 + f4);
        const float4 e0 = *(const float4*)(zs_in + (size_t)s0.w * 16 + f4);
        const float4 a1 = *(const float4*)(zs_in + (size_t)s1.x * 16 + f4);
        const float4 b1 = *(const float4*)(zs_in + (size_t)s1.y * 16 + f4);
        const float4 c1 = *(const float4*)(zs_in + (size_t)s1.z * 16 + f4);
        const float4 e1 = *(const float4*)(zs_in + (size_t)s1.w * 16 + f4);
        S.x += ((a0.x + b0.x) + (c0.x + e0.x)) + ((a1.x + b1.x) + (c1.x + e1.x));
        S.y += ((a0.y + b0.y) + (c0.y + e0.y)) + ((a1.y + b1.y) + (c1.y + e1.y));
        S.z += ((a0.z + b0.z) + (c0.z + e0.z)) + ((a1.z + b1.z) + (c1.z + e1.z));
        S.w += ((a0.w + b0.w) + (c0.w + e0.w)) + ((a1.w + b1.w) + (c1.w + e1.w));
    }
    if (j < re) {
        int4 s0 = *(const int4*)(csr_s + j);
        const float4 a0 = *(const float4*)(zs_in + (size_t)s0.x * 16 + f4);
        const float4 b0 = *(const float4*)(zs_in + (size_t)s0.y * 16 + f4);
        const float4 c0 = *(const float4*)(zs_in + (size_t)s0.z * 16 + f4);
        const float4 e0 = *(const float4*)(zs_in + (size_t)s0.w * 16 + f4);
        S.x += (a0.x + b0.x) + (c0.x + e0.x);
        S.y += (a0.y + b0.y) + (c0.y + e0.y);
        S.z += (a0.z + b0.z) + (c0.z + e0.z);
        S.w += (a0.w + b0.w) + (c0.w + e0.w);
    }

    // combine the 4 sub partial sums (all 16 lanes end with the full sum)
    S.x += __shfl_xor(S.x, 4); S.y += __shfl_xor(S.y, 4);
    S.z += __shfl_xor(S.z, 4); S.w += __shfl_xor(S.w, 4);
    S.x += __shfl_xor(S.x, 8); S.y += __shfl_xor(S.y, 8);
    S.z += __shfl_xor(S.z, 8); S.w += __shfl_xor(S.w, 8);

    // self-loop contribution
    const float4 self = *(const float4*)(zs_in + (size_t)d * 16 + f4);
    S.x += self.x; S.y += self.y; S.z += self.z; S.w += self.w;

    const float di = dinv[d];
    const float4 hv = *(const float4*)(hmat + (size_t)d * 16 + f4);
    float4 zn;
    zn.x = fmaf(1.0f - ALPHA, di * S.x, ALPHA * hv.x);
    zn.y = fmaf(1.0f - ALPHA, di * S.y, ALPHA * hv.y);
    zn.z = fmaf(1.0f - ALPHA, di * S.z, ALPHA * hv.z);
    zn.w = fmaf(1.0f - ALPHA, di * S.w, ALPHA * hv.w);
    if (!is_last) {
        if (sub == 0)
            *(float4*)(out + (size_t)d * 16 + f4) =
                make_float4(di * zn.x, di * zn.y, di * zn.z, di * zn.w);
    } else {
        float m = fmaxf(fmaxf(zn.x, zn.y), fmaxf(zn.z, zn.w));
        m = fmaxf(m, __shfl_xor(m, 1));
        m = fmaxf(m, __shfl_xor(m, 2));
        float ss = expf(zn.x - m) + expf(zn.y - m) + expf(zn.z - m) + expf(zn.w - m);
        ss += __shfl_xor(ss, 1);
        ss += __shfl_xor(ss, 2);
        float ls = logf(ss);
        if (sub == 0)
            *(float4*)(out + (size_t)d * 16 + f4) =
                make_float4(zn.x - m - ls, zn.y - m - ls, zn.z - m - ls, zn.w - m - ls);
    }
}

// ---------------------------------------------------------------------------
extern "C" void kernel_launch(void* const* d_in, const int* in_sizes, int n_in,
                              void* d_out, int out_size, void* d_ws, size_t ws_size,
                              hipStream_t stream)
{
    const float* x  = (const float*)d_in[0];
    const float* W1 = (const float*)d_in[1];
    const float* b1 = (const float*)d_in[2];
    const float* W2 = (const float*)d_in[3];
    const float* b2 = (const float*)d_in[4];
    const int*   ei = (const int*)d_in[5];

    const int N = N_NODES;
    const int E = N_EDGES;
    const int EP_MAX = 4800000;                 // >= E + 15*N worst-case padded
    const int* srcp = ei;
    const int* dstp = ei + E;

    float* ws = (float*)d_ws;
    float* h       = ws;                        // 1,600,000 f
    float* ZSA     = ws + 1600000;              // 1,600,016 f (row N = dummy zeros)
    float* ZSB     = ws + 3200016;              // 1,600,016 f (starts as hs)
    float* dinv    = ws + 4800032;              // 100,000 f
    int*   row_st  = (int*)(ws + 4900032);      // 100,001 i (pad 100004)
    int*   csr_s   = (int*)(ws + 5000036);      // up to 4,800,000 x 4B
    // transient overlays (dead before mlp writes h):
    int*   cnt     = (int*)(ws);                // 100,000
    int*   cursor  = (int*)(ws + 100000);       // 100,000
    int*   bsum    = (int*)(ws + 200000);       // 512
    int*   boff    = (int*)(ws + 200512);       // 512
    int*   pcnt    = (int*)(ws + 201024);       // 100,000
    uint4* W1f     = (uint4*)(ws + 1600000);    // in ZSA region (dead before step 0)
    float* zsA_dummy = ZSA + (size_t)N * 16;
    float* zsB_dummy = ZSB + (size_t)N * 16;

    const int NB_SCAN = (N + 255) / 256;        // 391 (covers i <= N)

    hipMemsetAsync(cnt, 0, (size_t)N * sizeof(int), stream);
    hist_kernel<<<(E + 255) / 256, 256, 0, stream>>>(dstp, cnt, E);
    dinv_kernel<<<(N + 255) / 256, 256, 0, stream>>>(cnt, dinv, pcnt,
                                                     zsA_dummy, zsB_dummy, N);
    fill_kernel<<<(EP_MAX / 4 + 255) / 256, 256, 0, stream>>>((int4*)csr_s, N, EP_MAX / 4);
    scan1_kernel<<<NB_SCAN, 256, 0, stream>>>(pcnt, row_st, bsum, N);
    scan2_kernel<<<1, 512, 0, stream>>>(bsum, boff, NB_SCAN);
    scan3_kernel<<<(N + 256) / 256, 256, 0, stream>>>(row_st, boff, cursor, N);
    {
        const int nchunks = (E + SC_CHUNK - 1) / SC_CHUNK;   // 1563
        scatter8_kernel<<<nchunks * 8, 256, 0, stream>>>(srcp, dstp, cursor, csr_s, E);
    }
    w1_frag_kernel<<<64, 256, 0, stream>>>(W1, W1f);
    mlp_kernel<<<(N + 63) / 64, 256, 0, stream>>>(x, W1f, b1, W2, b2, dinv, h, ZSB, N);

    const int NB_PROP = (N + 15) / 16;   // 6250 blocks, 16 nodes/block
    for (int k = 0; k < 10; ++k) {
        const int last = (k == 9) ? 1 : 0;
        const float* zin = (k == 0) ? ZSB : ((k & 1) ? ZSA : ZSB);
        float* zo = last ? (float*)d_out : ((k & 1) ? ZSB : ZSA);
        prop_kernel<<<NB_PROP, 256, 0, stream>>>(csr_s, row_st, dinv, zin, h, zo,
                                                 N, last);
    }
}